// Round 4
// baseline (25952.191 us; speedup 1.0000x reference)
//
#include <hip/hip_runtime.h>
#include <stdint.h>

// E=8 experts, C=1024, H=2048, I=4096.
//   gate_up = X @ Wgu ; act = silu(gate)*up ; out = act @ Wd
// Round 4: transpose+convert+silu all fused into the GEMMs.
//  - A operand: bf16, global_load_lds staged, [rows][64B] XOR-swizzled LDS.
//  - B operand: native f32 [K][N] weights, reg-staged (16 coalesced dwords /
//    thread / K-tile), v_cvt_pk_bf16_f32 packed, conflict-free ds_write_b128
//    into [4 kg][256 n][16B] LDS tile. B prefetch depth 2 (two reg banks),
//    A depth 1; counted vmcnt (16+AOPS / 16), ONE barrier per K-tile.
//  - GEMM1 B-tile interleaves gate|up columns so silu pairs live in one
//    thread's acc; epilogue writes act bf16 directly.
//  - Flattened grid + bijective XCD chunking: one expert per XCD, bm
//    innermost so B panels are L2-resident.

#define E_  8
#define C_  1024
#define H_  2048
#define I_  4096
#define N1_ 8192   // 2*I

typedef __bf16 bf16x8 __attribute__((ext_vector_type(8)));
typedef float  f32x4  __attribute__((ext_vector_type(4)));

typedef __attribute__((address_space(3))) unsigned       lds_uint;
typedef const __attribute__((address_space(1))) unsigned glob_uint;

__device__ __forceinline__ void gload_lds16(const void* g, void* l) {
    __builtin_amdgcn_global_load_lds((glob_uint*)g, (lds_uint*)l, 16, 0, 0);
}

__device__ __forceinline__ unsigned short f2bf(float f) {
    union { float f; unsigned u; } v; v.f = f;
    unsigned u = v.u;
    return (unsigned short)((u + 0x7FFFu + ((u >> 16) & 1u)) >> 16);  // RNE
}

// ---------------- elementwise fp32 -> bf16 (X only) ----------------
__global__ void k_convert(const float* __restrict__ src,
                          unsigned short* __restrict__ dst, int n8) {
    int idx = blockIdx.x * blockDim.x + threadIdx.x;
    int stride = gridDim.x * blockDim.x;
    for (int i = idx; i < n8; i += stride) {
        const float4* s = reinterpret_cast<const float4*>(src + (size_t)i * 8);
        float4 a = s[0], b = s[1];
        ushort4 lo, hi;
        lo.x = f2bf(a.x); lo.y = f2bf(a.y); lo.z = f2bf(a.z); lo.w = f2bf(a.w);
        hi.x = f2bf(b.x); hi.y = f2bf(b.y); hi.z = f2bf(b.z); hi.w = f2bf(b.w);
        ushort4* d = reinterpret_cast<ushort4*>(dst + (size_t)i * 8);
        d[0] = lo; d[1] = hi;
    }
}

// ---------------- helpers ----------------
template<int N> __device__ __forceinline__ void waitvm() {
    if constexpr (N == 0)  asm volatile("s_waitcnt vmcnt(0)"  ::: "memory");
    if constexpr (N == 1)  asm volatile("s_waitcnt vmcnt(1)"  ::: "memory");
    if constexpr (N == 2)  asm volatile("s_waitcnt vmcnt(2)"  ::: "memory");
    if constexpr (N == 16) asm volatile("s_waitcnt vmcnt(16)" ::: "memory");
    if constexpr (N == 17) asm volatile("s_waitcnt vmcnt(17)" ::: "memory");
    if constexpr (N == 18) asm volatile("s_waitcnt vmcnt(18)" ::: "memory");
}

// A staging: [BM rows][64B] row-major, XOR swizzle kb^=(row&3)<<4 applied at
// the pre-swizzled global source (global_load_lds dest is lane-linear).
template<int LD, int AOPS>
__device__ __forceinline__ void stageA(const char* __restrict__ gtile,
                                       char* ldst, int tid, int wave) {
    #pragma unroll
    for (int l = 0; l < AOPS; ++l) {
        unsigned p   = (unsigned)(l * 8192 + tid * 16);
        unsigned row = p >> 6;
        unsigned kb  = (p & 63u) ^ ((row & 3u) << 4);
        const char* gp = gtile + (size_t)row * LD + kb;
        void* lp = ldst + l * 8192 + wave * 1024;
        gload_lds16(gp, lp);
    }
}

__device__ __forceinline__ const bf16x8* frag_at(const char* lds_tile, int row, int kbl) {
    unsigned phys = (unsigned)(row * 64) + ((unsigned)kbl ^ (((unsigned)row & 3u) << 4));
    return reinterpret_cast<const bf16x8*>(lds_tile + phys);
}

// B: 16 strided-dword column loads (lanes have consecutive cols -> coalesced)
template<int LDB_E>
__device__ __forceinline__ void loadB16(const float* __restrict__ bcol, int kt,
                                        int kh, float (&v)[16]) {
    const float* p = bcol + ((size_t)kt * 32 + (size_t)kh * 16) * LDB_E;
    #pragma unroll
    for (int i = 0; i < 16; ++i) v[i] = p[(size_t)i * LDB_E];
}

// pack 16 f32 (k-consecutive) -> 2x b128 into [kg][n][16B]; lanes contiguous.
__device__ __forceinline__ void packWriteB(char* bdst, const float (&v)[16],
                                           int nn, int kh) {
    unsigned u[8];
    #pragma unroll
    for (int q2 = 0; q2 < 8; ++q2)
        asm("v_cvt_pk_bf16_f32 %0, %1, %2"
            : "=v"(u[q2]) : "v"(v[2 * q2]), "v"(v[2 * q2 + 1]));
    *reinterpret_cast<uint4*>(bdst + (kh * 2    ) * 4096 + nn * 16) =
        make_uint4(u[0], u[1], u[2], u[3]);
    *reinterpret_cast<uint4*>(bdst + (kh * 2 + 1) * 4096 + nn * 16) =
        make_uint4(u[4], u[5], u[6], u[7]);
}

#define TILE_ITER(T, CB, NB, ISS, WRB) do {                                    \
    if ((T) + 1 < NT) stageA<LDA_B, AOPS>(gA + (size_t)((T) + 1) * 64, (NB), tid, wave); \
    __builtin_amdgcn_sched_barrier(0);                                         \
    if ((T) + 2 < NT) loadB16<LDB_E>(bcol, (T) + 2, kh, (ISS));                \
    __builtin_amdgcn_sched_barrier(0);                                         \
    bf16x8 aF[MR]; bf16x8 bF[NR];                                              \
    _Pragma("unroll")                                                          \
    for (int m = 0; m < MR; ++m)                                               \
        aF[m] = *frag_at((CB), wm * (MR * 16) + m * 16 + r, kbl);              \
    _Pragma("unroll")                                                          \
    for (int n = 0; n < NR; ++n)                                               \
        bF[n] = *reinterpret_cast<const bf16x8*>(                              \
            (CB) + ABYTES + kg * 4096 + (size_t)(wn * (NR * 16) + n * 16 + r) * 16); \
    asm volatile("s_waitcnt lgkmcnt(0)" ::: "memory");                         \
    __builtin_amdgcn_sched_barrier(0);                                         \
    __builtin_amdgcn_s_setprio(1);                                             \
    _Pragma("unroll")                                                          \
    for (int m = 0; m < MR; ++m)                                               \
        _Pragma("unroll")                                                      \
        for (int n = 0; n < NR; ++n)                                           \
            acc[m][n] = __builtin_amdgcn_mfma_f32_16x16x32_bf16(               \
                aF[m], bF[n], acc[m][n], 0, 0, 0);                             \
    __builtin_amdgcn_s_setprio(0);                                             \
    __builtin_amdgcn_sched_barrier(0);                                         \
    if ((T) + 1 < NT) {                                                        \
        if ((T) + 2 < NT) waitvm<16 + AOPS>(); else waitvm<AOPS>();            \
        __builtin_amdgcn_sched_barrier(0);                                     \
        packWriteB((NB) + ABYTES, (WRB), nn, kh);                              \
        if ((T) + 2 < NT) waitvm<16>(); else waitvm<0>();                      \
        asm volatile("s_waitcnt lgkmcnt(0)" ::: "memory");                     \
        __builtin_amdgcn_sched_barrier(0);                                     \
        __builtin_amdgcn_s_barrier();                                          \
        __builtin_amdgcn_sched_barrier(0);                                     \
    }                                                                          \
} while (0)

// MODE 0: gemm1 (B=Wgu, gate|up interleaved cols, silu epilogue -> bf16 act)
// MODE 1: gemm2 (B=Wd, f32 out)
template<int LDA_B, int LDB_E, int NT, int BMG, int BNG,
         int MR, int NR, int WMC, int WNC, int MODE>
__global__ __launch_bounds__(512, 4) void k_gemm_f(
    const unsigned short* __restrict__ A,
    const float* __restrict__ B,
    void* __restrict__ Cout) {
    constexpr int BM = WMC * MR * 16;
    constexpr int ABYTES = BM * 64;
    constexpr int AOPS = ABYTES / (512 * 16);
    constexpr int BUF = ABYTES + 16384;
    static_assert(WNC * NR * 16 == 256, "BN must be 256");
    __shared__ char lds[2 * BUF];
    char* buf0 = lds;
    char* buf1 = lds + BUF;

    const int tid = threadIdx.x, lane = tid & 63, wave = tid >> 6;
    int wm, wn;
    if constexpr (WNC == 4) { wm = wave >> 2; wn = wave & 3; }
    else                    { wm = wave & 3;  wn = wave >> 2; }
    const int kg = lane >> 4, r = lane & 15, kbl = kg * 16;
    const int nn = tid & 255, kh = tid >> 8;

    // flattened grid, bijective XCD chunking (gridDim.x % 8 == 0)
    unsigned flat = blockIdx.x;
    unsigned cpx = gridDim.x >> 3;
    unsigned nid = (flat & 7u) * cpx + (flat >> 3);
    const int bm = nid % BMG;
    const int bn = (nid / BMG) % BNG;
    const int e  = nid / (BMG * BNG);

    const char* gA = (const char*)(A + (size_t)e * C_ * (LDA_B / 2))
                   + (size_t)bm * BM * LDA_B;
    size_t col;
    if constexpr (MODE == 0)
        col = (size_t)bn * 128 + (size_t)((nn >> 6) << 5) + (nn & 31)
            + ((nn & 32) ? (size_t)I_ : (size_t)0);
    else
        col = (size_t)bn * 256 + nn;
    const float* bcol = B + (size_t)e * ((size_t)(NT * 32) * LDB_E) + col;

    float bk0[16], bk1[16];
    f32x4 acc[MR][NR] = {};

    // prologue: A(0); B(0)->bk0; B(1)->bk1; wait A(0)+B(0); write B(0); barrier
    stageA<LDA_B, AOPS>(gA, buf0, tid, wave);
    __builtin_amdgcn_sched_barrier(0);
    loadB16<LDB_E>(bcol, 0, kh, bk0);
    __builtin_amdgcn_sched_barrier(0);
    loadB16<LDB_E>(bcol, 1, kh, bk1);
    __builtin_amdgcn_sched_barrier(0);
    waitvm<16>();
    __builtin_amdgcn_sched_barrier(0);
    packWriteB(buf0 + ABYTES, bk0, nn, kh);
    asm volatile("s_waitcnt lgkmcnt(0)" ::: "memory");
    __builtin_amdgcn_sched_barrier(0);
    __builtin_amdgcn_s_barrier();
    __builtin_amdgcn_sched_barrier(0);

    for (int t = 0; t < NT; t += 2) {
        TILE_ITER(t,     buf0, buf1, bk0, bk1);
        TILE_ITER(t + 1, buf1, buf0, bk1, bk0);
    }

    // ---------------- epilogue ----------------
    if constexpr (MODE == 0) {
        unsigned short* act = (unsigned short*)Cout + (size_t)e * C_ * I_;
        const int row0 = bm * BM + wm * (MR * 16) + kg * 4;
        const int col0 = bn * 128 + wn * 32 + r;
        #pragma unroll
        for (int m = 0; m < MR; ++m)
            #pragma unroll
            for (int n = 0; n < 2; ++n)
                #pragma unroll
                for (int j = 0; j < 4; ++j) {
                    float g = acc[m][n][j], u = acc[m][n + 2][j];
                    float s = g / (1.0f + __expf(-g)) * u;
                    act[(size_t)(row0 + m * 16 + j) * I_ + col0 + n * 16] = f2bf(s);
                }
    } else {
        float* o = (float*)Cout + (size_t)e * C_ * H_;
        const int row0 = bm * BM + wm * (MR * 16) + kg * 4;
        const int col0 = bn * 256 + wn * (NR * 16) + r;
        #pragma unroll
        for (int m = 0; m < MR; ++m)
            #pragma unroll
            for (int n = 0; n < NR; ++n)
                #pragma unroll
                for (int j = 0; j < 4; ++j)
                    o[(size_t)(row0 + m * 16 + j) * H_ + col0 + n * 16] = acc[m][n][j];
    }
}

// ---------------- launch ----------------
extern "C" void kernel_launch(void* const* d_in, const int* in_sizes, int n_in,
                              void* d_out, int out_size, void* d_ws, size_t ws_size,
                              hipStream_t stream) {
    const float* hs  = (const float*)d_in[0];   // [E][C][H]
    const float* wgu = (const float*)d_in[1];   // [E][H][2I]
    const float* wd  = (const float*)d_in[2];   // [E][I][H]
    float* out = (float*)d_out;

    char* ws = (char*)d_ws;
    unsigned short* Xbf  = (unsigned short*)(ws);                 // 33,554,432 B
    unsigned short* actb = (unsigned short*)(ws + 33554432ull);   // 67,108,864 B

    k_convert<<<2048, 256, 0, stream>>>(hs, Xbf, E_ * C_ * H_ / 8);

    // GEMM1: X[EC][H] x Wgu(native [H][2I]) -> act bf16 [EC][I]
    // BM=256 (BMG=4), 128 act cols/block (BNG=32), NT=64. 1024 blocks.
    k_gemm_f<H_ * 2, N1_, H_ / 32, 4, 32, 8, 4, 2, 4, 0>
        <<<dim3(1024), 512, 0, stream>>>(Xbf, wgu, actb);

    // GEMM2: act[EC][I] x Wd(native [I][H]) -> out f32 [EC][H]
    // BM=128 (BMG=8), BN=256 (BNG=8), NT=128. 512 blocks.
    k_gemm_f<I_ * 2, H_, I_ / 32, 8, 8, 2, 8, 4, 2, 1>
        <<<dim3(512), 512, 0, stream>>>(actb, wd, out);
}

// Round 5
// 835.804 us; speedup vs baseline: 31.0506x; 31.0506x over previous
//
#include <hip/hip_runtime.h>
#include <stdint.h>

// E=8 experts, C=1024, H=2048, I=4096.
//   gate_up = X @ Wgu ; act = silu(gate)*up ; out = act @ Wd
// Round 5: round-4 fused structure (transpose+convert+silu inside the GEMMs),
// register-pressure fixed:
//  - __launch_bounds__(512, 2)  (round-4's (512,4) capped regs at 128 ->
//    accumulator spill to scratch -> 66 GB HBM traffic. Guideline 6.)
//  - Both GEMMs BM=128, BN=256, MR=4, NR=4: acc=64 (AGPR), aF+bF=64,
//    bk0/bk1=32 -> ~210 regs, fits 256-budget at 2 blocks/CU.
//  - A: bf16 global_load_lds, [128 rows][64B] XOR-swizzled LDS (AOPS=1).
//  - B: native f32 [K][N], 16 coalesced strided dwords/thread/K-tile,
//    v_cvt_pk_bf16_f32, conflict-free ds_write_b128 into [4][256][16B].
//    B reg-prefetch depth 2; counted vmcnt(17)/vmcnt(16); ONE barrier/K-tile.
//  - GEMM1 interleaves gate|up cols so silu pairs share a thread's acc.
//  - Flattened grid + bijective XCD chunking: exactly one expert per XCD,
//    bm innermost (B panel shared by 8 consecutive blocks).

#define E_  8
#define C_  1024
#define H_  2048
#define I_  4096
#define N1_ 8192   // 2*I

typedef __bf16 bf16x8 __attribute__((ext_vector_type(8)));
typedef float  f32x4  __attribute__((ext_vector_type(4)));

typedef __attribute__((address_space(3))) unsigned       lds_uint;
typedef const __attribute__((address_space(1))) unsigned glob_uint;

__device__ __forceinline__ void gload_lds16(const void* g, void* l) {
    __builtin_amdgcn_global_load_lds((glob_uint*)g, (lds_uint*)l, 16, 0, 0);
}

__device__ __forceinline__ unsigned short f2bf(float f) {
    union { float f; unsigned u; } v; v.f = f;
    unsigned u = v.u;
    return (unsigned short)((u + 0x7FFFu + ((u >> 16) & 1u)) >> 16);  // RNE
}

// ---------------- elementwise fp32 -> bf16 (X only) ----------------
__global__ void k_convert(const float* __restrict__ src,
                          unsigned short* __restrict__ dst, int n8) {
    int idx = blockIdx.x * blockDim.x + threadIdx.x;
    int stride = gridDim.x * blockDim.x;
    for (int i = idx; i < n8; i += stride) {
        const float4* s = reinterpret_cast<const float4*>(src + (size_t)i * 8);
        float4 a = s[0], b = s[1];
        ushort4 lo, hi;
        lo.x = f2bf(a.x); lo.y = f2bf(a.y); lo.z = f2bf(a.z); lo.w = f2bf(a.w);
        hi.x = f2bf(b.x); hi.y = f2bf(b.y); hi.z = f2bf(b.z); hi.w = f2bf(b.w);
        ushort4* d = reinterpret_cast<ushort4*>(dst + (size_t)i * 8);
        d[0] = lo; d[1] = hi;
    }
}

// ---------------- helpers ----------------
template<int N> __device__ __forceinline__ void waitvm() {
    if constexpr (N == 0)  asm volatile("s_waitcnt vmcnt(0)"  ::: "memory");
    if constexpr (N == 1)  asm volatile("s_waitcnt vmcnt(1)"  ::: "memory");
    if constexpr (N == 16) asm volatile("s_waitcnt vmcnt(16)" ::: "memory");
    if constexpr (N == 17) asm volatile("s_waitcnt vmcnt(17)" ::: "memory");
}

// A staging: [128 rows][64B] row-major, XOR swizzle kb^=(row&3)<<4 applied at
// the pre-swizzled global source (global_load_lds dest is lane-linear).
template<int LD>
__device__ __forceinline__ void stageA(const char* __restrict__ gtile,
                                       char* ldst, int tid, int wave) {
    unsigned p   = (unsigned)(tid * 16);
    unsigned row = p >> 6;
    unsigned kb  = (p & 63u) ^ ((row & 3u) << 4);
    const char* gp = gtile + (size_t)row * LD + kb;
    void* lp = ldst + wave * 1024;   // wave-uniform base
    gload_lds16(gp, lp);
}

__device__ __forceinline__ const bf16x8* frag_at(const char* lds_tile, int row, int kbl) {
    unsigned phys = (unsigned)(row * 64) + ((unsigned)kbl ^ (((unsigned)row & 3u) << 4));
    return reinterpret_cast<const bf16x8*>(lds_tile + phys);
}

// B: 16 strided-dword column loads (lanes have consecutive cols -> coalesced)
template<int LDB_E>
__device__ __forceinline__ void loadB16(const float* __restrict__ bcol, int kt,
                                        int kh, float (&v)[16]) {
    const float* p = bcol + ((size_t)kt * 32 + (size_t)kh * 16) * LDB_E;
    #pragma unroll
    for (int i = 0; i < 16; ++i) v[i] = p[(size_t)i * LDB_E];
}

// pack 16 f32 (k-consecutive) -> 2x b128 into [kg][256 n][16B]; lanes contiguous.
__device__ __forceinline__ void packWriteB(char* bdst, const float (&v)[16],
                                           int nn, int kh) {
    unsigned u[8];
    #pragma unroll
    for (int q2 = 0; q2 < 8; ++q2)
        asm("v_cvt_pk_bf16_f32 %0, %1, %2"
            : "=v"(u[q2]) : "v"(v[2 * q2]), "v"(v[2 * q2 + 1]));
    *reinterpret_cast<uint4*>(bdst + (kh * 2    ) * 4096 + nn * 16) =
        make_uint4(u[0], u[1], u[2], u[3]);
    *reinterpret_cast<uint4*>(bdst + (kh * 2 + 1) * 4096 + nn * 16) =
        make_uint4(u[4], u[5], u[6], u[7]);
}

#define TILE_ITER(T, CB, NB, ISS, WRB) do {                                    \
    if ((T) + 1 < NT) stageA<LDA_B>(gA + (size_t)((T) + 1) * 64, (NB), tid, wave); \
    __builtin_amdgcn_sched_barrier(0);                                         \
    if ((T) + 2 < NT) loadB16<LDB_E>(bcol, (T) + 2, kh, (ISS));                \
    __builtin_amdgcn_sched_barrier(0);                                         \
    bf16x8 aF[4]; bf16x8 bF[4];                                                \
    _Pragma("unroll")                                                          \
    for (int m = 0; m < 4; ++m)                                                \
        aF[m] = *frag_at((CB), wm * 64 + m * 16 + r, kbl);                     \
    _Pragma("unroll")                                                          \
    for (int n = 0; n < 4; ++n)                                                \
        bF[n] = *reinterpret_cast<const bf16x8*>(                              \
            (CB) + ABYTES + kg * 4096 + (size_t)(wn * 64 + n * 16 + r) * 16);  \
    asm volatile("s_waitcnt lgkmcnt(0)" ::: "memory");                         \
    __builtin_amdgcn_sched_barrier(0);                                         \
    __builtin_amdgcn_s_setprio(1);                                             \
    _Pragma("unroll")                                                          \
    for (int m = 0; m < 4; ++m)                                                \
        _Pragma("unroll")                                                      \
        for (int n = 0; n < 4; ++n)                                            \
            acc[m][n] = __builtin_amdgcn_mfma_f32_16x16x32_bf16(               \
                aF[m], bF[n], acc[m][n], 0, 0, 0);                             \
    __builtin_amdgcn_s_setprio(0);                                             \
    __builtin_amdgcn_sched_barrier(0);                                         \
    if ((T) + 1 < NT) {                                                        \
        if ((T) + 2 < NT) waitvm<17>(); else waitvm<1>();                      \
        __builtin_amdgcn_sched_barrier(0);                                     \
        packWriteB((NB) + ABYTES, (WRB), nn, kh);                              \
        if ((T) + 2 < NT) waitvm<16>(); else waitvm<0>();                      \
        asm volatile("s_waitcnt lgkmcnt(0)" ::: "memory");                     \
        __builtin_amdgcn_sched_barrier(0);                                     \
        __builtin_amdgcn_s_barrier();                                          \
        __builtin_amdgcn_sched_barrier(0);                                     \
    }                                                                          \
} while (0)

// MODE 0: gemm1 (B=Wgu, gate|up interleaved cols, silu epilogue -> bf16 act)
// MODE 1: gemm2 (B=Wd, f32 out)
// BM=128 (wm in {0,1}, 4 m-frags), BN=256 (wn in {0..3}, 4 n-frags).
template<int LDA_B, int LDB_E, int NT, int BMG, int BNG, int MODE>
__global__ __launch_bounds__(512, 2) void k_gemm_f(
    const unsigned short* __restrict__ A,
    const float* __restrict__ B,
    void* __restrict__ Cout) {
    constexpr int ABYTES = 128 * 64;          // 8192
    constexpr int BUF = ABYTES + 16384;       // 24576; 2 buffers = 48 KiB
    __shared__ char lds[2 * BUF];
    char* buf0 = lds;
    char* buf1 = lds + BUF;

    const int tid = threadIdx.x, lane = tid & 63, wave = tid >> 6;
    const int wm = wave >> 2, wn = wave & 3;
    const int kg = lane >> 4, r = lane & 15, kbl = kg * 16;
    const int nn = tid & 255, kh = tid >> 8;

    // flattened grid, bijective XCD chunking (gridDim.x % 8 == 0)
    unsigned flat = blockIdx.x;
    unsigned cpx = gridDim.x >> 3;
    unsigned nid = (flat & 7u) * cpx + (flat >> 3);
    const int bm = nid % BMG;
    const int bn = (nid / BMG) % BNG;
    const int e  = nid / (BMG * BNG);

    const char* gA = (const char*)(A + (size_t)e * C_ * (LDA_B / 2))
                   + (size_t)bm * 128 * LDA_B;
    size_t col;
    if constexpr (MODE == 0)
        col = (size_t)bn * 128 + (size_t)((nn >> 6) << 5) + (nn & 31)
            + ((nn & 32) ? (size_t)I_ : (size_t)0);
    else
        col = (size_t)bn * 256 + nn;
    const float* bcol = B + (size_t)e * ((size_t)(NT * 32) * LDB_E) + col;

    float bk0[16], bk1[16];
    f32x4 acc[4][4] = {};

    // prologue: A(0); B(0)->bk0; B(1)->bk1; wait; write B(0); barrier
    stageA<LDA_B>(gA, buf0, tid, wave);
    __builtin_amdgcn_sched_barrier(0);
    loadB16<LDB_E>(bcol, 0, kh, bk0);
    __builtin_amdgcn_sched_barrier(0);
    loadB16<LDB_E>(bcol, 1, kh, bk1);
    __builtin_amdgcn_sched_barrier(0);
    waitvm<16>();
    __builtin_amdgcn_sched_barrier(0);
    packWriteB(buf0 + ABYTES, bk0, nn, kh);
    asm volatile("s_waitcnt lgkmcnt(0)" ::: "memory");
    __builtin_amdgcn_sched_barrier(0);
    __builtin_amdgcn_s_barrier();
    __builtin_amdgcn_sched_barrier(0);

    for (int t = 0; t < NT; t += 2) {
        TILE_ITER(t,     buf0, buf1, bk0, bk1);
        TILE_ITER(t + 1, buf1, buf0, bk1, bk0);
    }

    // ---------------- epilogue ----------------
    if constexpr (MODE == 0) {
        unsigned short* act = (unsigned short*)Cout + (size_t)e * C_ * I_;
        const int row0 = bm * 128 + wm * 64 + kg * 4;
        const int col0 = bn * 128 + wn * 32 + r;
        #pragma unroll
        for (int m = 0; m < 4; ++m)
            #pragma unroll
            for (int n = 0; n < 2; ++n)
                #pragma unroll
                for (int j = 0; j < 4; ++j) {
                    float g = acc[m][n][j], u = acc[m][n + 2][j];
                    float s = g / (1.0f + __expf(-g)) * u;
                    act[(size_t)(row0 + m * 16 + j) * I_ + col0 + n * 16] = f2bf(s);
                }
    } else {
        float* o = (float*)Cout + (size_t)e * C_ * H_;
        const int row0 = bm * 128 + wm * 64 + kg * 4;
        const int col0 = bn * 256 + wn * 64 + r;
        #pragma unroll
        for (int m = 0; m < 4; ++m)
            #pragma unroll
            for (int n = 0; n < 4; ++n)
                #pragma unroll
                for (int j = 0; j < 4; ++j)
                    o[(size_t)(row0 + m * 16 + j) * H_ + col0 + n * 16] = acc[m][n][j];
    }
}

// ---------------- launch ----------------
extern "C" void kernel_launch(void* const* d_in, const int* in_sizes, int n_in,
                              void* d_out, int out_size, void* d_ws, size_t ws_size,
                              hipStream_t stream) {
    const float* hs  = (const float*)d_in[0];   // [E][C][H]
    const float* wgu = (const float*)d_in[1];   // [E][H][2I]
    const float* wd  = (const float*)d_in[2];   // [E][I][H]
    float* out = (float*)d_out;

    char* ws = (char*)d_ws;
    unsigned short* Xbf  = (unsigned short*)(ws);                 // 33,554,432 B
    unsigned short* actb = (unsigned short*)(ws + 33554432ull);   // 67,108,864 B

    k_convert<<<2048, 256, 0, stream>>>(hs, Xbf, E_ * C_ * H_ / 8);

    // GEMM1: X[EC][H] x Wgu(native [H][2I]) -> act bf16 [EC][I]
    // BM=128 (BMG=8), 128 act cols/block (BNG=32), NT=64. 2048 blocks.
    // XCD chunk = 256 blocks = exactly one expert per XCD, bm innermost.
    k_gemm_f<H_ * 2, N1_, H_ / 32, 8, 32, 0>
        <<<dim3(2048), 512, 0, stream>>>(Xbf, wgu, actb);

    // GEMM2: act[EC][I] x Wd(native [I][H]) -> out f32 [EC][H]
    // BM=128 (BMG=8), BN=256 (BNG=8), NT=128. 512 blocks.
    k_gemm_f<I_ * 2, H_, I_ / 32, 8, 8, 1>
        <<<dim3(512), 512, 0, stream>>>(actb, wd, out);
}

// Round 6
// 635.885 us; speedup vs baseline: 40.8127x; 1.3144x over previous
//
#include <hip/hip_runtime.h>
#include <stdint.h>

// E=8 experts, C=1024, H=2048, I=4096.
//   gate_up = X @ Wgu ; act = silu(gate)*up ; out = act @ Wd
// Round 6: revert to round-3 GEMM core (256x256, BK=32, 3 LDS buffers,
// counted vmcnt(4), 0 bank conflicts, gload_lds both operands).
//  - silu fused into gemm1 epilogue via B-row permutation at the gload
//    SOURCE (LDS row q holds WguT row G(q) interleaving gate|up) so each
//    thread's acc[m][n]/acc[m][n+2] is a (gate,up) pair. No silu pass,
//    no gate_up buffer.
//  - k_transpose phase 2 remapped: 16 lanes write 128B contiguous runs.
//  - Flattened grid + bijective XCD chunking, bm innermost, one expert/XCD.

#define E_  8
#define C_  1024
#define H_  2048
#define I_  4096
#define N1_ 8192   // 2*I

typedef __bf16 bf16x8 __attribute__((ext_vector_type(8)));
typedef float  f32x4  __attribute__((ext_vector_type(4)));

typedef __attribute__((address_space(3))) unsigned       lds_uint;
typedef const __attribute__((address_space(1))) unsigned glob_uint;

__device__ __forceinline__ void gload_lds16(const void* g, void* l) {
    __builtin_amdgcn_global_load_lds((glob_uint*)g, (lds_uint*)l, 16, 0, 0);
}

__device__ __forceinline__ unsigned short f2bf(float f) {
    union { float f; unsigned u; } v; v.f = f;
    unsigned u = v.u;
    return (unsigned short)((u + 0x7FFFu + ((u >> 16) & 1u)) >> 16);  // RNE
}

// ---------------- elementwise fp32 -> bf16 (X only) ----------------
__global__ void k_convert(const float* __restrict__ src,
                          unsigned short* __restrict__ dst, int n8) {
    int idx = blockIdx.x * blockDim.x + threadIdx.x;
    int stride = gridDim.x * blockDim.x;
    for (int i = idx; i < n8; i += stride) {
        const float4* s = reinterpret_cast<const float4*>(src + (size_t)i * 8);
        float4 a = s[0], b = s[1];
        ushort4 lo, hi;
        lo.x = f2bf(a.x); lo.y = f2bf(a.y); lo.z = f2bf(a.z); lo.w = f2bf(a.w);
        hi.x = f2bf(b.x); hi.y = f2bf(b.y); hi.z = f2bf(b.z); hi.w = f2bf(b.w);
        ushort4* d = reinterpret_cast<ushort4*>(dst + (size_t)i * 8);
        d[0] = lo; d[1] = hi;
    }
}

// ---------------- tiled transpose + convert: [R][Cc] f32 -> [Cc][R] bf16 ----
// Phase 2 writes 128B-contiguous runs per output row (16 lanes x 8B).
__global__ void k_transpose(const float* __restrict__ src,
                            unsigned short* __restrict__ dst, int R, int Cc) {
    __shared__ unsigned short tile[64][68];
    const int e = blockIdx.z;
    const float* s = src + (size_t)e * R * Cc;
    unsigned short* d = dst + (size_t)e * R * Cc;
    const int r0 = blockIdx.y * 64;
    const int c0 = blockIdx.x * 64;
    const int t = threadIdx.x;
    {
        int row = t >> 4;           // 0..15
        int col = (t & 15) * 4;     // 0..60
        #pragma unroll
        for (int i = 0; i < 4; ++i) {
            int rr = row + i * 16;
            float4 v = *reinterpret_cast<const float4*>(s + (size_t)(r0 + rr) * Cc + c0 + col);
            ushort4 b;
            b.x = f2bf(v.x); b.y = f2bf(v.y); b.z = f2bf(v.z); b.w = f2bf(v.w);
            *reinterpret_cast<ushort4*>(&tile[rr][col]) = b;
        }
    }
    __syncthreads();
    {
        const int l = t & 15;       // output-column group (source rows 4l..4l+3)
        const int g = t >> 4;       // 0..15
        #pragma unroll
        for (int p = 0; p < 4; ++p) {
            int oc = p * 16 + g;    // output row = original col
            ushort4 b;
            b.x = tile[4 * l + 0][oc];
            b.y = tile[4 * l + 1][oc];
            b.z = tile[4 * l + 2][oc];
            b.w = tile[4 * l + 3][oc];
            *reinterpret_cast<ushort4*>(d + (size_t)(c0 + oc) * R + r0 + 4 * l) = b;
        }
    }
}

// ---------------- 256x256 GEMM core (round-3 proven) ----------------
// LDS per buffer: A [256 row][64B] (16 KiB, XOR swizzle kb^=(row&3)<<4) + B
// same; 3 buffers (96 KiB). Stage via gload_lds16 with pre-swizzled source.
// PERM: B LDS row q sources WguT row (q>>6)*32+((q>>4)&1)*16+(q&15)
//       +((q>>5)&1)*I  (relative to bn*128 base) -> gate|up interleave.
template<int LD, bool PERM>
__device__ __forceinline__ void stage2(const char* __restrict__ gtile,
                                       char* ldst, int tid, int wave) {
    #pragma unroll
    for (int l = 0; l < 2; ++l) {
        unsigned p   = (unsigned)(l * 8192 + tid * 16);
        unsigned row = p >> 6;
        unsigned kb  = (p & 63u) ^ ((row & 3u) << 4);
        size_t grow;
        if constexpr (PERM)
            grow = (size_t)((row >> 6) * 32 + ((row >> 4) & 1u) * 16 + (row & 15u))
                 + (size_t)((row >> 5) & 1u) * I_;
        else
            grow = row;
        const char* gp = gtile + grow * LD + kb;
        void* lp = ldst + l * 8192 + wave * 1024;   // wave-uniform base
        gload_lds16(gp, lp);
    }
}

__device__ __forceinline__ const bf16x8* frag_at(const char* lds_tile, int row, int kbl) {
    unsigned phys = (unsigned)(row * 64) + ((unsigned)kbl ^ (((unsigned)row & 3u) << 4));
    return reinterpret_cast<const bf16x8*>(lds_tile + phys);
}

// MODE 0: gemm1 (B=WguT with gate|up row-perm, silu epilogue -> bf16 act)
// MODE 1: gemm2 (plain, f32 out)
template<int LD, int NT, int BMG, int BNG, int MODE>
__global__ __launch_bounds__(512, 2) void k_gemm(
    const unsigned short* __restrict__ A,
    const unsigned short* __restrict__ B,
    void* __restrict__ Cout,
    size_t sA, size_t sB) {
    __shared__ char lds[3 * 32768];

    const int tid = threadIdx.x, lane = tid & 63, wave = tid >> 6;
    const int wm = wave >> 2, wn = wave & 3;
    const int kg = lane >> 4, r = lane & 15;
    const int kbl = kg * 16;

    // flattened grid, bijective XCD chunking (gridDim.x % 8 == 0), bm innermost
    unsigned flat = blockIdx.x;
    unsigned cpx = gridDim.x >> 3;
    unsigned nid = (flat & 7u) * cpx + (flat >> 3);
    const int bm = nid % BMG;
    const int bn = (nid / BMG) % BNG;
    const int e  = nid / (BMG * BNG);

    const char* gA = (const char*)(A + sA * e) + (size_t)(bm * 256) * LD;
    const char* gB = (const char*)(B + sB * e)
                   + (size_t)(bn * (MODE == 0 ? 128 : 256)) * LD;

    // prologue: stage tiles 0 and 1
    stage2<LD, false>(gA,      lds,                 tid, wave);
    stage2<LD, MODE == 0>(gB,      lds + 16384,         tid, wave);
    stage2<LD, false>(gA + 64, lds + 32768,         tid, wave);
    stage2<LD, MODE == 0>(gB + 64, lds + 32768 + 16384, tid, wave);
    asm volatile("s_waitcnt vmcnt(4)" ::: "memory");
    __builtin_amdgcn_sched_barrier(0);
    __builtin_amdgcn_s_barrier();
    __builtin_amdgcn_sched_barrier(0);

    f32x4 acc[8][4] = {};
    int cur = 0;

    for (int t = 0; t < NT; ++t) {
        char* cb = lds + cur * 32768;
        const char* Ab = cb;
        const char* Bb = cb + 16384;
        const int st = (cur == 0) ? 2 : cur - 1;   // (cur+2)%3
        char* sb = lds + st * 32768;
        const size_t ko = (size_t)(t + 2) * 64;    // k byte offset of tile t+2

        // ---------------- phase 0: m0-3 ----------------
        bf16x8 aF[4], bF[4];
        #pragma unroll
        for (int m = 0; m < 4; ++m)
            aF[m] = *frag_at(Ab, wm * 128 + m * 16 + r, kbl);
        #pragma unroll
        for (int n = 0; n < 4; ++n)
            bF[n] = *frag_at(Bb, wn * 64 + n * 16 + r, kbl);
        if (t + 2 < NT) stage2<LD, false>(gA + ko, sb, tid, wave);
        __builtin_amdgcn_sched_barrier(0);
        __builtin_amdgcn_s_barrier();
        asm volatile("s_waitcnt lgkmcnt(0)" ::: "memory");
        __builtin_amdgcn_sched_barrier(0);
        __builtin_amdgcn_s_setprio(1);
        #pragma unroll
        for (int m = 0; m < 4; ++m)
            #pragma unroll
            for (int n = 0; n < 4; ++n)
                acc[m][n] = __builtin_amdgcn_mfma_f32_16x16x32_bf16(
                    aF[m], bF[n], acc[m][n], 0, 0, 0);
        __builtin_amdgcn_s_setprio(0);
        __builtin_amdgcn_sched_barrier(0);
        __builtin_amdgcn_s_barrier();
        __builtin_amdgcn_sched_barrier(0);

        // ---------------- phase 1: m4-7 ----------------
        bf16x8 aG[4];
        #pragma unroll
        for (int m = 0; m < 4; ++m)
            aG[m] = *frag_at(Ab, wm * 128 + (m + 4) * 16 + r, kbl);
        if (t + 2 < NT) stage2<LD, MODE == 0>(gB + ko, sb + 16384, tid, wave);
        __builtin_amdgcn_sched_barrier(0);
        __builtin_amdgcn_s_barrier();
        asm volatile("s_waitcnt lgkmcnt(0)" ::: "memory");
        __builtin_amdgcn_sched_barrier(0);
        __builtin_amdgcn_s_setprio(1);
        #pragma unroll
        for (int m = 0; m < 4; ++m)
            #pragma unroll
            for (int n = 0; n < 4; ++n)
                acc[m + 4][n] = __builtin_amdgcn_mfma_f32_16x16x32_bf16(
                    aG[m], bF[n], acc[m + 4][n], 0, 0, 0);
        __builtin_amdgcn_s_setprio(0);
        __builtin_amdgcn_sched_barrier(0);
        if (t == NT - 2) { asm volatile("s_waitcnt vmcnt(0)" ::: "memory"); }
        else             { asm volatile("s_waitcnt vmcnt(4)" ::: "memory"); }
        __builtin_amdgcn_sched_barrier(0);
        __builtin_amdgcn_s_barrier();
        __builtin_amdgcn_sched_barrier(0);

        cur = (cur == 2) ? 0 : cur + 1;
    }

    // ---------------- epilogue ----------------
    const int row0 = bm * 256 + wm * 128 + kg * 4;   // + m*16 + j
    if constexpr (MODE == 0) {
        // acc[m][n] (n<2) = gate col bn*128+wn*32+n*16+r; acc[m][n+2] = up.
        unsigned short* act = (unsigned short*)Cout + (size_t)e * C_ * I_;
        const int col0 = bn * 128 + wn * 32 + r;
        #pragma unroll
        for (int m = 0; m < 8; ++m)
            #pragma unroll
            for (int n = 0; n < 2; ++n)
                #pragma unroll
                for (int j = 0; j < 4; ++j) {
                    float g = acc[m][n][j], u = acc[m][n + 2][j];
                    float s = g / (1.0f + __expf(-g)) * u;
                    act[(size_t)(row0 + m * 16 + j) * I_ + col0 + n * 16] = f2bf(s);
                }
    } else {
        float* o = (float*)Cout + (size_t)e * C_ * H_;
        const int col0 = bn * 256 + wn * 64 + r;
        #pragma unroll
        for (int m = 0; m < 8; ++m)
            #pragma unroll
            for (int n = 0; n < 4; ++n)
                #pragma unroll
                for (int j = 0; j < 4; ++j)
                    o[(size_t)(row0 + m * 16 + j) * H_ + col0 + n * 16] = acc[m][n][j];
    }
}

// ---------------- launch ----------------
extern "C" void kernel_launch(void* const* d_in, const int* in_sizes, int n_in,
                              void* d_out, int out_size, void* d_ws, size_t ws_size,
                              hipStream_t stream) {
    const float* hs  = (const float*)d_in[0];   // [E][C][H]
    const float* wgu = (const float*)d_in[1];   // [E][H][2I]
    const float* wd  = (const float*)d_in[2];   // [E][I][H]
    float* out = (float*)d_out;

    char* ws = (char*)d_ws;
    unsigned short* Xbf  = (unsigned short*)(ws);                 //  33,554,432 B
    unsigned short* WguT = (unsigned short*)(ws +  33554432ull);  // 268,435,456 B
    unsigned short* WdT  = (unsigned short*)(ws + 301989888ull);  // 134,217,728 B
    unsigned short* actb = (unsigned short*)(ws + 436207616ull);  //  67,108,864 B
    // total: 503,316,480 bytes

    k_convert<<<2048, 256, 0, stream>>>(hs, Xbf, E_ * C_ * H_ / 8);

    dim3 tg1(N1_ / 64, H_ / 64, E_);   // Wgu [H][2I] -> WguT [2I][H]
    k_transpose<<<tg1, 256, 0, stream>>>(wgu, WguT, H_, N1_);

    // GEMM1 (fused silu): X[EC][H] x WguT(perm) -> act bf16 [EC][I]
    // BM=256 (BMG=4), 128 act cols/block (BNG=32), NT=64. 1024 blocks;
    // XCD chunk = 128 blocks = one expert per XCD, bm innermost.
    k_gemm<H_ * 2, H_ / 32, 4, 32, 0><<<dim3(1024), 512, 0, stream>>>(
        Xbf, WguT, actb, (size_t)C_ * H_, (size_t)N1_ * H_);

    dim3 tg2(H_ / 64, I_ / 64, E_);    // Wd [I][H] -> WdT [H][I]
    k_transpose<<<tg2, 256, 0, stream>>>(wd, WdT, I_, H_);

    // GEMM2: act[EC][I] x WdT[H][I] -> out f32 [EC][H]
    // BM=256 (BMG=4), BN=256 (BNG=8), NT=128. 256 blocks; 32/XCD = one expert.
    k_gemm<I_ * 2, I_ / 32, 4, 8, 1><<<dim3(256), 512, 0, stream>>>(
        actb, WdT, out, (size_t)C_ * I_, (size_t)H_ * I_);
}

// Round 7
// 622.967 us; speedup vs baseline: 41.6590x; 1.0207x over previous
//
#include <hip/hip_runtime.h>
#include <stdint.h>

// E=8 experts, C=1024, H=2048, I=4096.
//   gate_up = X @ Wgu ; act = silu(gate)*up ; out = act @ Wd
// Round 7: round-6 structure, ONE change: LDS XOR swizzle constant
// (row&3)<<4 -> ((row>>1)&3)<<4. Round-6's swizzle gave bank-quad
// q=(row&1)*4+(kg^(row&3)) with period 4 over the 16 rows a 16-lane group
// reads -> 4-way conflict (SQ_LDS_BANK_CONFLICT=2.5e7, 1.58x LDS cost).
// New constant: q=(row&1)*4+(kg^((row>>1)&3)) takes 8 distinct quads over
// rows 0..7 -> 2-way (free). Applied identically at gload source and
// ds_read (involution, rule 21). Global coalescing unchanged (permutation
// stays within each row's 64B window).

#define E_  8
#define C_  1024
#define H_  2048
#define I_  4096
#define N1_ 8192   // 2*I

typedef __bf16 bf16x8 __attribute__((ext_vector_type(8)));
typedef float  f32x4  __attribute__((ext_vector_type(4)));

typedef __attribute__((address_space(3))) unsigned       lds_uint;
typedef const __attribute__((address_space(1))) unsigned glob_uint;

__device__ __forceinline__ void gload_lds16(const void* g, void* l) {
    __builtin_amdgcn_global_load_lds((glob_uint*)g, (lds_uint*)l, 16, 0, 0);
}

__device__ __forceinline__ unsigned short f2bf(float f) {
    union { float f; unsigned u; } v; v.f = f;
    unsigned u = v.u;
    return (unsigned short)((u + 0x7FFFu + ((u >> 16) & 1u)) >> 16);  // RNE
}

// ---------------- elementwise fp32 -> bf16 (X only) ----------------
__global__ void k_convert(const float* __restrict__ src,
                          unsigned short* __restrict__ dst, int n8) {
    int idx = blockIdx.x * blockDim.x + threadIdx.x;
    int stride = gridDim.x * blockDim.x;
    for (int i = idx; i < n8; i += stride) {
        const float4* s = reinterpret_cast<const float4*>(src + (size_t)i * 8);
        float4 a = s[0], b = s[1];
        ushort4 lo, hi;
        lo.x = f2bf(a.x); lo.y = f2bf(a.y); lo.z = f2bf(a.z); lo.w = f2bf(a.w);
        hi.x = f2bf(b.x); hi.y = f2bf(b.y); hi.z = f2bf(b.z); hi.w = f2bf(b.w);
        ushort4* d = reinterpret_cast<ushort4*>(dst + (size_t)i * 8);
        d[0] = lo; d[1] = hi;
    }
}

// ---------------- tiled transpose + convert: [R][Cc] f32 -> [Cc][R] bf16 ----
// Phase 2 writes 128B-contiguous runs per output row (16 lanes x 8B).
__global__ void k_transpose(const float* __restrict__ src,
                            unsigned short* __restrict__ dst, int R, int Cc) {
    __shared__ unsigned short tile[64][68];
    const int e = blockIdx.z;
    const float* s = src + (size_t)e * R * Cc;
    unsigned short* d = dst + (size_t)e * R * Cc;
    const int r0 = blockIdx.y * 64;
    const int c0 = blockIdx.x * 64;
    const int t = threadIdx.x;
    {
        int row = t >> 4;           // 0..15
        int col = (t & 15) * 4;     // 0..60
        #pragma unroll
        for (int i = 0; i < 4; ++i) {
            int rr = row + i * 16;
            float4 v = *reinterpret_cast<const float4*>(s + (size_t)(r0 + rr) * Cc + c0 + col);
            ushort4 b;
            b.x = f2bf(v.x); b.y = f2bf(v.y); b.z = f2bf(v.z); b.w = f2bf(v.w);
            *reinterpret_cast<ushort4*>(&tile[rr][col]) = b;
        }
    }
    __syncthreads();
    {
        const int l = t & 15;       // output-column group (source rows 4l..4l+3)
        const int g = t >> 4;       // 0..15
        #pragma unroll
        for (int p = 0; p < 4; ++p) {
            int oc = p * 16 + g;    // output row = original col
            ushort4 b;
            b.x = tile[4 * l + 0][oc];
            b.y = tile[4 * l + 1][oc];
            b.z = tile[4 * l + 2][oc];
            b.w = tile[4 * l + 3][oc];
            *reinterpret_cast<ushort4*>(d + (size_t)(c0 + oc) * R + r0 + 4 * l) = b;
        }
    }
}

// ---------------- 256x256 GEMM core ----------------
// LDS per buffer: A [256 row][64B] (16 KiB, XOR swizzle kb^=((row>>1)&3)<<4)
// + B same; 3 buffers (96 KiB). Stage via gload_lds16 with pre-swizzled src.
// PERM: B LDS row q sources WguT row (q>>6)*32+((q>>4)&1)*16+(q&15)
//       +((q>>5)&1)*I  (relative to bn*128 base) -> gate|up interleave.
template<int LD, bool PERM>
__device__ __forceinline__ void stage2(const char* __restrict__ gtile,
                                       char* ldst, int tid, int wave) {
    #pragma unroll
    for (int l = 0; l < 2; ++l) {
        unsigned p   = (unsigned)(l * 8192 + tid * 16);
        unsigned row = p >> 6;
        unsigned kb  = (p & 63u) ^ (((row >> 1) & 3u) << 4);
        size_t grow;
        if constexpr (PERM)
            grow = (size_t)((row >> 6) * 32 + ((row >> 4) & 1u) * 16 + (row & 15u))
                 + (size_t)((row >> 5) & 1u) * I_;
        else
            grow = row;
        const char* gp = gtile + grow * LD + kb;
        void* lp = ldst + l * 8192 + wave * 1024;   // wave-uniform base
        gload_lds16(gp, lp);
    }
}

__device__ __forceinline__ const bf16x8* frag_at(const char* lds_tile, int row, int kbl) {
    unsigned phys = (unsigned)(row * 64)
                  + ((unsigned)kbl ^ ((((unsigned)row >> 1) & 3u) << 4));
    return reinterpret_cast<const bf16x8*>(lds_tile + phys);
}

// MODE 0: gemm1 (B=WguT with gate|up row-perm, silu epilogue -> bf16 act)
// MODE 1: gemm2 (plain, f32 out)
template<int LD, int NT, int BMG, int BNG, int MODE>
__global__ __launch_bounds__(512, 2) void k_gemm(
    const unsigned short* __restrict__ A,
    const unsigned short* __restrict__ B,
    void* __restrict__ Cout,
    size_t sA, size_t sB) {
    __shared__ char lds[3 * 32768];

    const int tid = threadIdx.x, lane = tid & 63, wave = tid >> 6;
    const int wm = wave >> 2, wn = wave & 3;
    const int kg = lane >> 4, r = lane & 15;
    const int kbl = kg * 16;

    // flattened grid, bijective XCD chunking (gridDim.x % 8 == 0), bm innermost
    unsigned flat = blockIdx.x;
    unsigned cpx = gridDim.x >> 3;
    unsigned nid = (flat & 7u) * cpx + (flat >> 3);
    const int bm = nid % BMG;
    const int bn = (nid / BMG) % BNG;
    const int e  = nid / (BMG * BNG);

    const char* gA = (const char*)(A + sA * e) + (size_t)(bm * 256) * LD;
    const char* gB = (const char*)(B + sB * e)
                   + (size_t)(bn * (MODE == 0 ? 128 : 256)) * LD;

    // prologue: stage tiles 0 and 1
    stage2<LD, false>(gA,      lds,                 tid, wave);
    stage2<LD, MODE == 0>(gB,      lds + 16384,         tid, wave);
    stage2<LD, false>(gA + 64, lds + 32768,         tid, wave);
    stage2<LD, MODE == 0>(gB + 64, lds + 32768 + 16384, tid, wave);
    asm volatile("s_waitcnt vmcnt(4)" ::: "memory");
    __builtin_amdgcn_sched_barrier(0);
    __builtin_amdgcn_s_barrier();
    __builtin_amdgcn_sched_barrier(0);

    f32x4 acc[8][4] = {};
    int cur = 0;

    for (int t = 0; t < NT; ++t) {
        char* cb = lds + cur * 32768;
        const char* Ab = cb;
        const char* Bb = cb + 16384;
        const int st = (cur == 0) ? 2 : cur - 1;   // (cur+2)%3
        char* sb = lds + st * 32768;
        const size_t ko = (size_t)(t + 2) * 64;    // k byte offset of tile t+2

        // ---------------- phase 0: m0-3 ----------------
        bf16x8 aF[4], bF[4];
        #pragma unroll
        for (int m = 0; m < 4; ++m)
            aF[m] = *frag_at(Ab, wm * 128 + m * 16 + r, kbl);
        #pragma unroll
        for (int n = 0; n < 4; ++n)
            bF[n] = *frag_at(Bb, wn * 64 + n * 16 + r, kbl);
        if (t + 2 < NT) stage2<LD, false>(gA + ko, sb, tid, wave);
        __builtin_amdgcn_sched_barrier(0);
        __builtin_amdgcn_s_barrier();
        asm volatile("s_waitcnt lgkmcnt(0)" ::: "memory");
        __builtin_amdgcn_sched_barrier(0);
        __builtin_amdgcn_s_setprio(1);
        #pragma unroll
        for (int m = 0; m < 4; ++m)
            #pragma unroll
            for (int n = 0; n < 4; ++n)
                acc[m][n] = __builtin_amdgcn_mfma_f32_16x16x32_bf16(
                    aF[m], bF[n], acc[m][n], 0, 0, 0);
        __builtin_amdgcn_s_setprio(0);
        __builtin_amdgcn_sched_barrier(0);
        __builtin_amdgcn_s_barrier();
        __builtin_amdgcn_sched_barrier(0);

        // ---------------- phase 1: m4-7 ----------------
        bf16x8 aG[4];
        #pragma unroll
        for (int m = 0; m < 4; ++m)
            aG[m] = *frag_at(Ab, wm * 128 + (m + 4) * 16 + r, kbl);
        if (t + 2 < NT) stage2<LD, MODE == 0>(gB + ko, sb + 16384, tid, wave);
        __builtin_amdgcn_sched_barrier(0);
        __builtin_amdgcn_s_barrier();
        asm volatile("s_waitcnt lgkmcnt(0)" ::: "memory");
        __builtin_amdgcn_sched_barrier(0);
        __builtin_amdgcn_s_setprio(1);
        #pragma unroll
        for (int m = 0; m < 4; ++m)
            #pragma unroll
            for (int n = 0; n < 4; ++n)
                acc[m + 4][n] = __builtin_amdgcn_mfma_f32_16x16x32_bf16(
                    aG[m], bF[n], acc[m + 4][n], 0, 0, 0);
        __builtin_amdgcn_s_setprio(0);
        __builtin_amdgcn_sched_barrier(0);
        if (t == NT - 2) { asm volatile("s_waitcnt vmcnt(0)" ::: "memory"); }
        else             { asm volatile("s_waitcnt vmcnt(4)" ::: "memory"); }
        __builtin_amdgcn_sched_barrier(0);
        __builtin_amdgcn_s_barrier();
        __builtin_amdgcn_sched_barrier(0);

        cur = (cur == 2) ? 0 : cur + 1;
    }

    // ---------------- epilogue ----------------
    const int row0 = bm * 256 + wm * 128 + kg * 4;   // + m*16 + j
    if constexpr (MODE == 0) {
        // acc[m][n] (n<2) = gate col bn*128+wn*32+n*16+r; acc[m][n+2] = up.
        unsigned short* act = (unsigned short*)Cout + (size_t)e * C_ * I_;
        const int col0 = bn * 128 + wn * 32 + r;
        #pragma unroll
        for (int m = 0; m < 8; ++m)
            #pragma unroll
            for (int n = 0; n < 2; ++n)
                #pragma unroll
                for (int j = 0; j < 4; ++j) {
                    float g = acc[m][n][j], u = acc[m][n + 2][j];
                    float s = g / (1.0f + __expf(-g)) * u;
                    act[(size_t)(row0 + m * 16 + j) * I_ + col0 + n * 16] = f2bf(s);
                }
    } else {
        float* o = (float*)Cout + (size_t)e * C_ * H_;
        const int col0 = bn * 256 + wn * 64 + r;
        #pragma unroll
        for (int m = 0; m < 8; ++m)
            #pragma unroll
            for (int n = 0; n < 4; ++n)
                #pragma unroll
                for (int j = 0; j < 4; ++j)
                    o[(size_t)(row0 + m * 16 + j) * H_ + col0 + n * 16] = acc[m][n][j];
    }
}

// ---------------- launch ----------------
extern "C" void kernel_launch(void* const* d_in, const int* in_sizes, int n_in,
                              void* d_out, int out_size, void* d_ws, size_t ws_size,
                              hipStream_t stream) {
    const float* hs  = (const float*)d_in[0];   // [E][C][H]
    const float* wgu = (const float*)d_in[1];   // [E][H][2I]
    const float* wd  = (const float*)d_in[2];   // [E][I][H]
    float* out = (float*)d_out;

    char* ws = (char*)d_ws;
    unsigned short* Xbf  = (unsigned short*)(ws);                 //  33,554,432 B
    unsigned short* WguT = (unsigned short*)(ws +  33554432ull);  // 268,435,456 B
    unsigned short* WdT  = (unsigned short*)(ws + 301989888ull);  // 134,217,728 B
    unsigned short* actb = (unsigned short*)(ws + 436207616ull);  //  67,108,864 B
    // total: 503,316,480 bytes

    k_convert<<<2048, 256, 0, stream>>>(hs, Xbf, E_ * C_ * H_ / 8);

    dim3 tg1(N1_ / 64, H_ / 64, E_);   // Wgu [H][2I] -> WguT [2I][H]
    k_transpose<<<tg1, 256, 0, stream>>>(wgu, WguT, H_, N1_);

    // GEMM1 (fused silu): X[EC][H] x WguT(perm) -> act bf16 [EC][I]
    // BM=256 (BMG=4), 128 act cols/block (BNG=32), NT=64. 1024 blocks;
    // XCD chunk = 128 blocks = one expert per XCD, bm innermost.
    k_gemm<H_ * 2, H_ / 32, 4, 32, 0><<<dim3(1024), 512, 0, stream>>>(
        Xbf, WguT, actb, (size_t)C_ * H_, (size_t)N1_ * H_);

    dim3 tg2(H_ / 64, I_ / 64, E_);    // Wd [I][H] -> WdT [H][I]
    k_transpose<<<tg2, 256, 0, stream>>>(wd, WdT, I_, H_);

    // GEMM2: act[EC][I] x WdT[H][I] -> out f32 [EC][H]
    // BM=256 (BMG=4), BN=256 (BNG=8), NT=128. 256 blocks; 32/XCD = one expert.
    k_gemm<I_ * 2, I_ / 32, 4, 8, 1><<<dim3(256), 512, 0, stream>>>(
        actb, WdT, out, (size_t)C_ * I_, (size_t)H_ * I_);
}

// Round 8
// 598.692 us; speedup vs baseline: 43.3482x; 1.0405x over previous
//
#include <hip/hip_runtime.h>
#include <stdint.h>

// E=8 experts, C=1024, H=2048, I=4096.
//   gate_up = X @ Wgu ; act = silu(gate)*up ; out = act @ Wd
// Round 8: BK=64 4-phase schedule (m201-style). 2 LDS buffers (128 KiB),
// one barrier per phase (half of round 7's density), A-frags held across the
// K-tile (af[8][2]), counted vmcnt(2) at phases 0/3 only (derived from the
// staging issue order B0,B1|B2,B3|A0,A2|A1,A3), never 0 in the main loop.
// Swizzle for 128B rows: kb ^= (row&7)<<4 (2-way banks, coalescing kept).
// silu fused in gemm1 epilogue via the gate|up B-row permutation (round 6/7).

#define E_  8
#define C_  1024
#define H_  2048
#define I_  4096
#define N1_ 8192   // 2*I

typedef __bf16 bf16x8 __attribute__((ext_vector_type(8)));
typedef float  f32x4  __attribute__((ext_vector_type(4)));

typedef __attribute__((address_space(3))) unsigned       lds_uint;
typedef const __attribute__((address_space(1))) unsigned glob_uint;

__device__ __forceinline__ void gload_lds16(const void* g, void* l) {
    __builtin_amdgcn_global_load_lds((glob_uint*)g, (lds_uint*)l, 16, 0, 0);
}

__device__ __forceinline__ unsigned short f2bf(float f) {
    union { float f; unsigned u; } v; v.f = f;
    unsigned u = v.u;
    return (unsigned short)((u + 0x7FFFu + ((u >> 16) & 1u)) >> 16);  // RNE
}

// ---------------- elementwise fp32 -> bf16 (X only) ----------------
__global__ void k_convert(const float* __restrict__ src,
                          unsigned short* __restrict__ dst, int n8) {
    int idx = blockIdx.x * blockDim.x + threadIdx.x;
    int stride = gridDim.x * blockDim.x;
    for (int i = idx; i < n8; i += stride) {
        const float4* s = reinterpret_cast<const float4*>(src + (size_t)i * 8);
        float4 a = s[0], b = s[1];
        ushort4 lo, hi;
        lo.x = f2bf(a.x); lo.y = f2bf(a.y); lo.z = f2bf(a.z); lo.w = f2bf(a.w);
        hi.x = f2bf(b.x); hi.y = f2bf(b.y); hi.z = f2bf(b.z); hi.w = f2bf(b.w);
        ushort4* d = reinterpret_cast<ushort4*>(dst + (size_t)i * 8);
        d[0] = lo; d[1] = hi;
    }
}

// ---------------- tiled transpose + convert: [R][Cc] f32 -> [Cc][R] bf16 ----
__global__ void k_transpose(const float* __restrict__ src,
                            unsigned short* __restrict__ dst, int R, int Cc) {
    __shared__ unsigned short tile[64][68];
    const int e = blockIdx.z;
    const float* s = src + (size_t)e * R * Cc;
    unsigned short* d = dst + (size_t)e * R * Cc;
    const int r0 = blockIdx.y * 64;
    const int c0 = blockIdx.x * 64;
    const int t = threadIdx.x;
    {
        int row = t >> 4;           // 0..15
        int col = (t & 15) * 4;     // 0..60
        #pragma unroll
        for (int i = 0; i < 4; ++i) {
            int rr = row + i * 16;
            float4 v = *reinterpret_cast<const float4*>(s + (size_t)(r0 + rr) * Cc + c0 + col);
            ushort4 b;
            b.x = f2bf(v.x); b.y = f2bf(v.y); b.z = f2bf(v.z); b.w = f2bf(v.w);
            *reinterpret_cast<ushort4*>(&tile[rr][col]) = b;
        }
    }
    __syncthreads();
    {
        const int l = t & 15;
        const int g = t >> 4;
        #pragma unroll
        for (int p = 0; p < 4; ++p) {
            int oc = p * 16 + g;
            ushort4 b;
            b.x = tile[4 * l + 0][oc];
            b.y = tile[4 * l + 1][oc];
            b.z = tile[4 * l + 2][oc];
            b.w = tile[4 * l + 3][oc];
            *reinterpret_cast<ushort4*>(d + (size_t)(c0 + oc) * R + r0 + 4 * l) = b;
        }
    }
}

// ---------------- BK=64 staging & fragment access ----------------
// Tile region: [256 rows][128B], physical byte p: row=p>>7, off=p&127,
// logical kb = off ^ ((row&7)<<4)  (involution; bank-slot 2-way; within-row
// permutation keeps gload coalescing). Piece j = rows 64j..64j+63 (8 KiB).
template<int LD, bool PERM>
__device__ __forceinline__ void stageOp(const char* __restrict__ gbase,
                                        char* region, int j, int tid, int wave) {
    unsigned p   = (unsigned)(j * 8192 + tid * 16);
    unsigned row = p >> 7;
    unsigned kb  = (p & 127u) ^ ((row & 7u) << 4);
    size_t grow;
    if constexpr (PERM)
        grow = (size_t)((row >> 6) * 32 + ((row >> 4) & 1u) * 16 + (row & 15u))
             + (size_t)((row >> 5) & 1u) * I_;
    else
        grow = row;
    const char* gp = gbase + grow * (size_t)LD + kb;
    void* lp = region + j * 8192 + wave * 1024;   // wave-uniform base
    gload_lds16(gp, lp);
}

__device__ __forceinline__ const bf16x8* frag128(const char* tile, int row, int kb) {
    unsigned phys = (unsigned)(row * 128)
                  + ((unsigned)kb ^ (((unsigned)row & 7u) << 4));
    return reinterpret_cast<const bf16x8*>(tile + phys);
}

#define SBAR0 __builtin_amdgcn_sched_barrier(0)
#define MFMA_ __builtin_amdgcn_mfma_f32_16x16x32_bf16

// MODE 0: gemm1 (B=WguT with gate|up row-perm, silu epilogue -> bf16 act)
// MODE 1: gemm2 (plain, f32 out)
template<int LD, int NT, int BMG, int BNG, int MODE>
__global__ __launch_bounds__(512, 2) void k_gemm(
    const unsigned short* __restrict__ A,
    const unsigned short* __restrict__ B,
    void* __restrict__ Cout,
    size_t sA, size_t sB) {
    __shared__ char lds[2 * 65536];   // buf: A 32K | B 32K

    const int tid = threadIdx.x, lane = tid & 63, wave = tid >> 6;
    const int wm = wave >> 2, wn = wave & 3;
    const int kg = lane >> 4, r = lane & 15;

    // flattened grid, bijective XCD chunking (gridDim.x % 8 == 0), bm innermost
    unsigned flat = blockIdx.x;
    unsigned cpx = gridDim.x >> 3;
    unsigned nid = (flat & 7u) * cpx + (flat >> 3);
    const int bm = nid % BMG;
    const int bn = (nid / BMG) % BNG;
    const int e  = nid / (BMG * BNG);

    const char* gA = (const char*)(A + sA * e) + (size_t)(bm * 256) * LD;
    const char* gB = (const char*)(B + sB * e)
                   + (size_t)(bn * (MODE == 0 ? 128 : 256)) * LD;
    constexpr bool PB = (MODE == 0);

    // prologue: stage tile 0 in steady-state issue order; vmcnt(2)+barrier
    stageOp<LD, PB>(gB, lds + 32768, 0, tid, wave);
    stageOp<LD, PB>(gB, lds + 32768, 1, tid, wave);
    stageOp<LD, PB>(gB, lds + 32768, 2, tid, wave);
    stageOp<LD, PB>(gB, lds + 32768, 3, tid, wave);
    stageOp<LD, false>(gA, lds, 0, tid, wave);
    stageOp<LD, false>(gA, lds, 2, tid, wave);
    stageOp<LD, false>(gA, lds, 1, tid, wave);
    stageOp<LD, false>(gA, lds, 3, tid, wave);
    SBAR0;
    asm volatile("s_waitcnt vmcnt(2)" ::: "memory");
    SBAR0;
    __builtin_amdgcn_s_barrier();
    SBAR0;

    f32x4 acc[8][4] = {};

    for (int t = 0; t < NT; ++t) {
        const char* Ab = lds + (t & 1) * 65536;
        const char* Bb = Ab + 32768;
        char* sAr = lds + ((t + 1) & 1) * 65536;
        char* sBr = sAr + 32768;
        const char* gAn = gA + (size_t)(t + 1) * 128;
        const char* gBn = gB + (size_t)(t + 1) * 128;
        const bool hs = (t + 1) < NT;

        bf16x8 af[8][2], b0[2][2], bg[2][2];

        // ---- phase 0: quadrant (m0-3, n0-1) ----
        #pragma unroll
        for (int i = 0; i < 4; ++i)
            #pragma unroll
            for (int kk = 0; kk < 2; ++kk)
                af[i][kk] = *frag128(Ab, wm * 128 + i * 16 + r, kk * 64 + kg * 16);
        #pragma unroll
        for (int j = 0; j < 2; ++j)
            #pragma unroll
            for (int kk = 0; kk < 2; ++kk)
                b0[j][kk] = *frag128(Bb, wn * 64 + j * 16 + r, kk * 64 + kg * 16);
        if (hs) { stageOp<LD, PB>(gBn, sBr, 0, tid, wave);
                  stageOp<LD, PB>(gBn, sBr, 1, tid, wave); }
        SBAR0;
        if (hs) asm volatile("s_waitcnt vmcnt(2)" ::: "memory");
        else    asm volatile("s_waitcnt vmcnt(0)" ::: "memory");
        SBAR0;
        __builtin_amdgcn_s_barrier();
        asm volatile("s_waitcnt lgkmcnt(0)" ::: "memory");
        SBAR0;
        __builtin_amdgcn_s_setprio(1);
        #pragma unroll
        for (int mf = 0; mf < 4; ++mf)
            #pragma unroll
            for (int nf = 0; nf < 2; ++nf) {
                acc[mf][nf] = MFMA_(af[mf][0], b0[nf][0], acc[mf][nf], 0, 0, 0);
                acc[mf][nf] = MFMA_(af[mf][1], b0[nf][1], acc[mf][nf], 0, 0, 0);
            }
        __builtin_amdgcn_s_setprio(0);
        SBAR0;

        // ---- phase 1: quadrant (m4-7, n0-1) ----
        #pragma unroll
        for (int i = 4; i < 8; ++i)
            #pragma unroll
            for (int kk = 0; kk < 2; ++kk)
                af[i][kk] = *frag128(Ab, wm * 128 + i * 16 + r, kk * 64 + kg * 16);
        if (hs) { stageOp<LD, PB>(gBn, sBr, 2, tid, wave);
                  stageOp<LD, PB>(gBn, sBr, 3, tid, wave); }
        SBAR0;
        __builtin_amdgcn_s_barrier();
        asm volatile("s_waitcnt lgkmcnt(0)" ::: "memory");
        SBAR0;
        __builtin_amdgcn_s_setprio(1);
        #pragma unroll
        for (int mf = 4; mf < 8; ++mf)
            #pragma unroll
            for (int nf = 0; nf < 2; ++nf) {
                acc[mf][nf] = MFMA_(af[mf][0], b0[nf][0], acc[mf][nf], 0, 0, 0);
                acc[mf][nf] = MFMA_(af[mf][1], b0[nf][1], acc[mf][nf], 0, 0, 0);
            }
        __builtin_amdgcn_s_setprio(0);
        SBAR0;

        // ---- phase 2: quadrant (m4-7, n2-3) ----
        #pragma unroll
        for (int j = 0; j < 2; ++j)
            #pragma unroll
            for (int kk = 0; kk < 2; ++kk)
                bg[j][kk] = *frag128(Bb, wn * 64 + 32 + j * 16 + r, kk * 64 + kg * 16);
        if (hs) { stageOp<LD, false>(gAn, sAr, 0, tid, wave);
                  stageOp<LD, false>(gAn, sAr, 2, tid, wave); }
        SBAR0;
        __builtin_amdgcn_s_barrier();
        asm volatile("s_waitcnt lgkmcnt(0)" ::: "memory");
        SBAR0;
        __builtin_amdgcn_s_setprio(1);
        #pragma unroll
        for (int mf = 4; mf < 8; ++mf)
            #pragma unroll
            for (int nf = 0; nf < 2; ++nf) {
                acc[mf][nf + 2] = MFMA_(af[mf][0], bg[nf][0], acc[mf][nf + 2], 0, 0, 0);
                acc[mf][nf + 2] = MFMA_(af[mf][1], bg[nf][1], acc[mf][nf + 2], 0, 0, 0);
            }
        __builtin_amdgcn_s_setprio(0);
        SBAR0;

        // ---- phase 3: quadrant (m0-3, n2-3) ----
        if (hs) { stageOp<LD, false>(gAn, sAr, 1, tid, wave);
                  stageOp<LD, false>(gAn, sAr, 3, tid, wave); }
        SBAR0;
        if (hs) asm volatile("s_waitcnt vmcnt(2)" ::: "memory");
        SBAR0;
        __builtin_amdgcn_s_barrier();
        SBAR0;
        __builtin_amdgcn_s_setprio(1);
        #pragma unroll
        for (int mf = 0; mf < 4; ++mf)
            #pragma unroll
            for (int nf = 0; nf < 2; ++nf) {
                acc[mf][nf + 2] = MFMA_(af[mf][0], bg[nf][0], acc[mf][nf + 2], 0, 0, 0);
                acc[mf][nf + 2] = MFMA_(af[mf][1], bg[nf][1], acc[mf][nf + 2], 0, 0, 0);
            }
        __builtin_amdgcn_s_setprio(0);
        SBAR0;
    }

    // ---------------- epilogue ----------------
    const int row0 = bm * 256 + wm * 128 + kg * 4;   // + mf*16 + j
    if constexpr (MODE == 0) {
        // acc[mf][nf] (nf<2) = gate col bn*128+wn*32+nf*16+r; acc[mf][nf+2] = up.
        unsigned short* act = (unsigned short*)Cout + (size_t)e * C_ * I_;
        const int col0 = bn * 128 + wn * 32 + r;
        #pragma unroll
        for (int m = 0; m < 8; ++m)
            #pragma unroll
            for (int n = 0; n < 2; ++n)
                #pragma unroll
                for (int j = 0; j < 4; ++j) {
                    float g = acc[m][n][j], u = acc[m][n + 2][j];
                    float s = g / (1.0f + __expf(-g)) * u;
                    act[(size_t)(row0 + m * 16 + j) * I_ + col0 + n * 16] = f2bf(s);
                }
    } else {
        float* o = (float*)Cout + (size_t)e * C_ * H_;
        const int col0 = bn * 256 + wn * 64 + r;
        #pragma unroll
        for (int m = 0; m < 8; ++m)
            #pragma unroll
            for (int n = 0; n < 4; ++n)
                #pragma unroll
                for (int j = 0; j < 4; ++j)
                    o[(size_t)(row0 + m * 16 + j) * H_ + col0 + n * 16] = acc[m][n][j];
    }
}

// ---------------- launch ----------------
extern "C" void kernel_launch(void* const* d_in, const int* in_sizes, int n_in,
                              void* d_out, int out_size, void* d_ws, size_t ws_size,
                              hipStream_t stream) {
    const float* hs  = (const float*)d_in[0];   // [E][C][H]
    const float* wgu = (const float*)d_in[1];   // [E][H][2I]
    const float* wd  = (const float*)d_in[2];   // [E][I][H]
    float* out = (float*)d_out;

    char* ws = (char*)d_ws;
    unsigned short* Xbf  = (unsigned short*)(ws);                 //  33,554,432 B
    unsigned short* WguT = (unsigned short*)(ws +  33554432ull);  // 268,435,456 B
    unsigned short* WdT  = (unsigned short*)(ws + 301989888ull);  // 134,217,728 B
    unsigned short* actb = (unsigned short*)(ws + 436207616ull);  //  67,108,864 B
    // total: 503,316,480 bytes

    k_convert<<<2048, 256, 0, stream>>>(hs, Xbf, E_ * C_ * H_ / 8);

    dim3 tg1(N1_ / 64, H_ / 64, E_);   // Wgu [H][2I] -> WguT [2I][H]
    k_transpose<<<tg1, 256, 0, stream>>>(wgu, WguT, H_, N1_);

    // GEMM1 (fused silu): X[EC][H] x WguT(perm) -> act bf16 [EC][I]
    // BM=256 (BMG=4), 128 act cols/block (BNG=32), NT=32 (BK=64). 1024 blocks.
    k_gemm<H_ * 2, H_ / 64, 4, 32, 0><<<dim3(1024), 512, 0, stream>>>(
        Xbf, WguT, actb, (size_t)C_ * H_, (size_t)N1_ * H_);

    dim3 tg2(H_ / 64, I_ / 64, E_);    // Wd [I][H] -> WdT [H][I]
    k_transpose<<<tg2, 256, 0, stream>>>(wd, WdT, I_, H_);

    // GEMM2: act[EC][I] x WdT[H][I] -> out f32 [EC][H]
    // BM=256 (BMG=4), BN=256 (BNG=8), NT=64. 256 blocks.
    k_gemm<I_ * 2, I_ / 64, 4, 8, 1><<<dim3(256), 512, 0, stream>>>(
        actb, WdT, out, (size_t)C_ * I_, (size_t)H_ * I_);
}